// Round 4
// baseline (931.080 us; speedup 1.0000x reference)
//
#include <hip/hip_runtime.h>

#define N_NODESC 100000
#define N_EDGESC 1600000
#define BN_EPSC 1e-5f
#define NBUCK 1024          // coarse buckets (dst>>7), 782 non-empty
#define SBLK 256            // scatter/hist blocks
#define EPB (N_EDGESC / SBLK)   // 6250 edges per scatter block
#define HN (NBUCK * SBLK)   // 262144 hist entries

// ---------------------------------------------------------------------------
// K_hist_coarse: per-block histogram over 1024 coarse dst-buckets.
// Hm layout is bucket-major: Hm[b*SBLK + k] = count of block k's edges in b.
// ---------------------------------------------------------------------------
__global__ __launch_bounds__(1024) void k_hist_coarse(
    const int* __restrict__ ei, int* __restrict__ Hm)
{
    __shared__ int h[NBUCK];
    const int t = threadIdx.x;
    const int k = blockIdx.x;
    h[t] = 0;
    __syncthreads();
    const int base = k * EPB;
    #pragma unroll
    for (int i = 0; i < 7; i++) {
        const int e = base + i * 1024 + t;
        if (e < base + EPB) atomicAdd(&h[ei[N_EDGESC + e] >> 7], 1);
    }
    __syncthreads();
    Hm[t * SBLK + k] = h[t];
}

// ---------------------------------------------------------------------------
// K_scan1: per-block exclusive scan of 256 elems + block totals (1024 blocks).
// ---------------------------------------------------------------------------
__global__ __launch_bounds__(256) void k_scan1(
    const int* __restrict__ in, int* __restrict__ local, int* __restrict__ bsum)
{
    __shared__ int wsum[4];
    const int t = threadIdx.x;
    const int i = blockIdx.x * 256 + t;
    const int lane = t & 63;
    const int wid = t >> 6;
    const int v = in[i];
    int inc = v;
    #pragma unroll
    for (int d = 1; d < 64; d <<= 1) {
        const int u = __shfl_up(inc, d);
        if (lane >= d) inc += u;
    }
    if (lane == 63) wsum[wid] = inc;
    __syncthreads();
    int add = 0;
    #pragma unroll
    for (int w = 0; w < 3; w++) if (w < wid) add += wsum[w];
    local[i] = inc - v + add;
    if (t == 255) bsum[blockIdx.x] = add + inc;
}

// ---------------------------------------------------------------------------
// K_scan2: exclusive scan of the 1024 block totals (single block).
// ---------------------------------------------------------------------------
__global__ __launch_bounds__(1024) void k_scan2(
    const int* __restrict__ bsum, int* __restrict__ bsumx)
{
    __shared__ int s[1024];
    const int t = threadIdx.x;
    const int v = bsum[t];
    s[t] = v;
    __syncthreads();
    for (int d = 1; d < 1024; d <<= 1) {
        const int u = (t >= d) ? s[t - d] : 0;
        __syncthreads();
        s[t] += u;
        __syncthreads();
    }
    bsumx[t] = s[t] - v;
}

// ---------------------------------------------------------------------------
// K_scan3: S[i] = local[i] + bsumx[block].
// ---------------------------------------------------------------------------
__global__ __launch_bounds__(256) void k_scan3(
    const int* __restrict__ local, const int* __restrict__ bsumx,
    int* __restrict__ S)
{
    const int i = blockIdx.x * 256 + threadIdx.x;
    S[i] = local[i] + bsumx[blockIdx.x];
}

// ---------------------------------------------------------------------------
// K_scatter2: place edges into coarse buckets.  Block k's portion of bucket b
// is a contiguous range starting at S[b*SBLK+k] -> near-coalesced writes.
// packed = src(17b) | attr<<17 (2b) | (dst&127)<<19 (7b).
// ---------------------------------------------------------------------------
__global__ __launch_bounds__(1024) void k_scatter2(
    const int* __restrict__ ei, const int* __restrict__ ea,
    const int* __restrict__ S, int* __restrict__ packed)
{
    __shared__ int lcur[NBUCK];
    const int t = threadIdx.x;
    const int k = blockIdx.x;
    lcur[t] = S[t * SBLK + k];
    __syncthreads();
    const int base = k * EPB;
    #pragma unroll
    for (int i = 0; i < 7; i++) {
        const int e = base + i * 1024 + t;
        if (e < base + EPB) {
            const int src = ei[e];
            const int dst = ei[N_EDGESC + e];
            const int a = ea[e];
            const int pos = atomicAdd(&lcur[dst >> 7], 1);
            packed[pos] = src | (a << 17) | ((dst & 127) << 19);
        }
    }
}

// ---------------------------------------------------------------------------
// K_agg_lds: one block per bucket (128 nodes, 32KB LDS accumulator).
// One wave per edge: lane = feature; x-row load is 256B coalesced;
// ds_add_f32 banks alias exactly 2-way (free).  Edge words broadcast by shfl.
// ---------------------------------------------------------------------------
__global__ __launch_bounds__(256) void k_agg_lds(
    const float* __restrict__ x, const float* __restrict__ emb,
    const int* __restrict__ S, const int* __restrict__ packed,
    float* __restrict__ agg)
{
    __shared__ float acc[128 * 64];
    const int t = threadIdx.x;
    const int lane = t & 63;
    const int w = t >> 6;
    const int b = blockIdx.x;

    {   // zero accumulator
        float4* a4 = (float4*)acc;
        const float4 z = make_float4(0.f, 0.f, 0.f, 0.f);
        #pragma unroll
        for (int i = 0; i < 8; i++) a4[i * 256 + t] = z;
    }
    // preload the 4 embedding rows (this lane's feature)
    const float e0 = emb[lane];
    const float e1 = emb[64 + lane];
    const float e2 = emb[128 + lane];
    const float e3 = emb[192 + lane];
    __syncthreads();

    const int start = S[b * SBLK];
    const int end = S[(b + 1) * SBLK];
    for (int chunk = start + w * 64; chunk < end; chunk += 256) {
        const int mye = chunk + lane;
        const int pe = (mye < end) ? packed[mye] : 0;
        int cnt = end - chunk;
        if (cnt > 64) cnt = 64;
        for (int j = 0; j < cnt; j++) {
            const int p = __shfl(pe, j);
            const int src = p & 0x1FFFF;
            const int a = (p >> 17) & 3;
            const int nlo = (p >> 19) & 127;
            const float xv = x[(size_t)src * 64 + lane];
            const float ev = (a & 2) ? ((a & 1) ? e3 : e2) : ((a & 1) ? e1 : e0);
            atomicAdd(&acc[nlo * 64 + lane], fmaxf(xv + ev, 0.f));
        }
    }
    __syncthreads();

    {   // write 128 rows to agg (coalesced float4)
        const float4* a4 = (const float4*)acc;
        float4* o4 = (float4*)agg;
        #pragma unroll
        for (int i = 0; i < 8; i++) {
            const int fidx = i * 256 + t;
            const int node = b * 128 + (fidx >> 4);
            if (node < N_NODESC) o4[(size_t)node * 16 + (fidx & 15)] = a4[fidx];
        }
    }
}

// ---------------------------------------------------------------------------
// K_mlp1: hbuf := ((1+eps)*x + hbuf) @ W1 + b1 ; accumulate BN column sums.
// ---------------------------------------------------------------------------
__global__ __launch_bounds__(256) void k_mlp1(
    const float* __restrict__ x, float* hbuf,
    const float* __restrict__ W1, const float* __restrict__ b1,
    const float* __restrict__ epsp,
    float* __restrict__ cs, float* __restrict__ css)
{
    __shared__ float lin[64][68];
    __shared__ float lW[4096];
    __shared__ float redS[4][64];
    __shared__ float redQ[4][64];
    const int t = threadIdx.x;
    const int nbase = blockIdx.x * 64;
    const float sc1 = 1.0f + epsp[0];

    {
        const float4* W4 = (const float4*)W1;
        float4* lW4 = (float4*)lW;
        #pragma unroll
        for (int i = 0; i < 4; i++) lW4[i * 256 + t] = W4[i * 256 + t];
    }
    {
        const float4* x4 = (const float4*)x;
        const float4* a4 = (const float4*)hbuf;
        #pragma unroll
        for (int i = 0; i < 4; i++) {
            const int ln = i * 16 + (t >> 4);
            const int q = t & 15;
            const int n = nbase + ln;
            float4 v = make_float4(0.f, 0.f, 0.f, 0.f);
            if (n < N_NODESC) {
                const float4 xv = x4[(size_t)n * 16 + q];
                const float4 av = a4[(size_t)n * 16 + q];
                v.x = fmaf(sc1, xv.x, av.x);
                v.y = fmaf(sc1, xv.y, av.y);
                v.z = fmaf(sc1, xv.z, av.z);
                v.w = fmaf(sc1, xv.w, av.w);
            }
            *(float4*)&lin[ln][q * 4] = v;
        }
    }
    __syncthreads();

    const int r = t >> 2;
    const int g = t & 3;
    const int n = nbase + r;
    const float4* lW4 = (const float4*)lW;
    const float4* b4 = (const float4*)b1;
    float4 acc0 = b4[g * 4 + 0];
    float4 acc1 = b4[g * 4 + 1];
    float4 acc2 = b4[g * 4 + 2];
    float4 acc3 = b4[g * 4 + 3];
    for (int k = 0; k < 64; k++) {
        const float a = lin[r][k];
        const float4 w0 = lW4[k * 16 + g * 4 + 0];
        const float4 w1 = lW4[k * 16 + g * 4 + 1];
        const float4 w2 = lW4[k * 16 + g * 4 + 2];
        const float4 w3 = lW4[k * 16 + g * 4 + 3];
        acc0.x = fmaf(a, w0.x, acc0.x); acc0.y = fmaf(a, w0.y, acc0.y);
        acc0.z = fmaf(a, w0.z, acc0.z); acc0.w = fmaf(a, w0.w, acc0.w);
        acc1.x = fmaf(a, w1.x, acc1.x); acc1.y = fmaf(a, w1.y, acc1.y);
        acc1.z = fmaf(a, w1.z, acc1.z); acc1.w = fmaf(a, w1.w, acc1.w);
        acc2.x = fmaf(a, w2.x, acc2.x); acc2.y = fmaf(a, w2.y, acc2.y);
        acc2.z = fmaf(a, w2.z, acc2.z); acc2.w = fmaf(a, w2.w, acc2.w);
        acc3.x = fmaf(a, w3.x, acc3.x); acc3.y = fmaf(a, w3.y, acc3.y);
        acc3.z = fmaf(a, w3.z, acc3.z); acc3.w = fmaf(a, w3.w, acc3.w);
    }
    if (n < N_NODESC) {
        float4* h4 = (float4*)hbuf;
        h4[(size_t)n * 16 + g * 4 + 0] = acc0;
        h4[(size_t)n * 16 + g * 4 + 1] = acc1;
        h4[(size_t)n * 16 + g * 4 + 2] = acc2;
        h4[(size_t)n * 16 + g * 4 + 3] = acc3;
    }

    float vs[16], vq[16];
    const float msk = (n < N_NODESC) ? 1.0f : 0.0f;
    {
        const float a0[16] = {acc0.x, acc0.y, acc0.z, acc0.w,
                              acc1.x, acc1.y, acc1.z, acc1.w,
                              acc2.x, acc2.y, acc2.z, acc2.w,
                              acc3.x, acc3.y, acc3.z, acc3.w};
        #pragma unroll
        for (int i = 0; i < 16; i++) {
            const float v = a0[i] * msk;
            vs[i] = v;
            vq[i] = v * a0[i];
        }
    }
    #pragma unroll
    for (int off2 = 4; off2 < 64; off2 <<= 1) {
        #pragma unroll
        for (int i = 0; i < 16; i++) {
            vs[i] += __shfl_xor(vs[i], off2);
            vq[i] += __shfl_xor(vq[i], off2);
        }
    }
    const int lane = t & 63;
    const int w = t >> 6;
    if (lane < 4) {
        #pragma unroll
        for (int i = 0; i < 16; i++) {
            redS[w][lane * 16 + i] = vs[i];
            redQ[w][lane * 16 + i] = vq[i];
        }
    }
    __syncthreads();
    if (t < 64) {
        const float s = redS[0][t] + redS[1][t] + redS[2][t] + redS[3][t];
        const float qq = redQ[0][t] + redQ[1][t] + redQ[2][t] + redQ[3][t];
        unsafeAtomicAdd(&cs[t], s);
        unsafeAtomicAdd(&css[t], qq);
    }
}

// ---------------------------------------------------------------------------
// K_mlp2: out = relu(BN(h1)) @ W2 + b2.  h1 aliases out; rows staged to LDS.
// ---------------------------------------------------------------------------
__global__ __launch_bounds__(256) void k_mlp2(
    const float* h1, const float* __restrict__ W2, const float* __restrict__ b2,
    const float* __restrict__ gamma, const float* __restrict__ beta,
    const float* __restrict__ cs, const float* __restrict__ css,
    float* out)
{
    __shared__ float lin[64][68];
    __shared__ float lW[4096];
    __shared__ float scl[64];
    __shared__ float sft[64];
    const int t = threadIdx.x;
    const int nbase = blockIdx.x * 64;

    if (t < 64) {
        const float inv = 1.0f / (float)N_NODESC;
        const float mu = cs[t] * inv;
        const float var = css[t] * inv - mu * mu;
        const float rs = rsqrtf(var + BN_EPSC);
        const float s = rs * gamma[t];
        scl[t] = s;
        sft[t] = fmaf(-mu, s, beta[t]);
    }
    {
        const float4* W4 = (const float4*)W2;
        float4* lW4 = (float4*)lW;
        #pragma unroll
        for (int i = 0; i < 4; i++) lW4[i * 256 + t] = W4[i * 256 + t];
    }
    __syncthreads();
    {
        const float4* h4 = (const float4*)h1;
        #pragma unroll
        for (int i = 0; i < 4; i++) {
            const int ln = i * 16 + (t >> 4);
            const int q = t & 15;
            const int n = nbase + ln;
            float4 v = make_float4(0.f, 0.f, 0.f, 0.f);
            if (n < N_NODESC) {
                const float4 h = h4[(size_t)n * 16 + q];
                const int c = q * 4;
                v.x = fmaxf(fmaf(h.x, scl[c + 0], sft[c + 0]), 0.f);
                v.y = fmaxf(fmaf(h.y, scl[c + 1], sft[c + 1]), 0.f);
                v.z = fmaxf(fmaf(h.z, scl[c + 2], sft[c + 2]), 0.f);
                v.w = fmaxf(fmaf(h.w, scl[c + 3], sft[c + 3]), 0.f);
            }
            *(float4*)&lin[ln][q * 4] = v;
        }
    }
    __syncthreads();

    const int r = t >> 2;
    const int g = t & 3;
    const int n = nbase + r;
    const float4* lW4 = (const float4*)lW;
    const float4* b4 = (const float4*)b2;
    float4 acc0 = b4[g * 4 + 0];
    float4 acc1 = b4[g * 4 + 1];
    float4 acc2 = b4[g * 4 + 2];
    float4 acc3 = b4[g * 4 + 3];
    for (int k = 0; k < 64; k++) {
        const float a = lin[r][k];
        const float4 w0 = lW4[k * 16 + g * 4 + 0];
        const float4 w1 = lW4[k * 16 + g * 4 + 1];
        const float4 w2 = lW4[k * 16 + g * 4 + 2];
        const float4 w3 = lW4[k * 16 + g * 4 + 3];
        acc0.x = fmaf(a, w0.x, acc0.x); acc0.y = fmaf(a, w0.y, acc0.y);
        acc0.z = fmaf(a, w0.z, acc0.z); acc0.w = fmaf(a, w0.w, acc0.w);
        acc1.x = fmaf(a, w1.x, acc1.x); acc1.y = fmaf(a, w1.y, acc1.y);
        acc1.z = fmaf(a, w1.z, acc1.z); acc1.w = fmaf(a, w1.w, acc1.w);
        acc2.x = fmaf(a, w2.x, acc2.x); acc2.y = fmaf(a, w2.y, acc2.y);
        acc2.z = fmaf(a, w2.z, acc2.z); acc2.w = fmaf(a, w2.w, acc2.w);
        acc3.x = fmaf(a, w3.x, acc3.x); acc3.y = fmaf(a, w3.y, acc3.y);
        acc3.z = fmaf(a, w3.z, acc3.z); acc3.w = fmaf(a, w3.w, acc3.w);
    }
    if (n < N_NODESC) {
        float4* o4 = (float4*)out;
        o4[(size_t)n * 16 + g * 4 + 0] = acc0;
        o4[(size_t)n * 16 + g * 4 + 1] = acc1;
        o4[(size_t)n * 16 + g * 4 + 2] = acc2;
        o4[(size_t)n * 16 + g * 4 + 3] = acc3;
    }
}

// ---------------------------------------------------------------------------
extern "C" void kernel_launch(void* const* d_in, const int* in_sizes, int n_in,
                              void* d_out, int out_size, void* d_ws, size_t ws_size,
                              hipStream_t stream) {
    const float* x     = (const float*)d_in[0];
    const float* emb   = (const float*)d_in[1];
    const float* eps   = (const float*)d_in[2];
    const float* W1    = (const float*)d_in[3];
    const float* b1    = (const float*)d_in[4];
    const float* gamma = (const float*)d_in[5];
    const float* beta  = (const float*)d_in[6];
    const float* W2    = (const float*)d_in[7];
    const float* b2    = (const float*)d_in[8];
    const int*   ei    = (const int*)d_in[9];
    const int*   ea    = (const int*)d_in[10];
    float* out = (float*)d_out;

    // ws: [cs 64][css 64][Hm 262144][Sloc 262144][bsum 1024][bsumx 1024]
    //     [S 262144][packed E]   (~9.6 MB)
    float* ws    = (float*)d_ws;
    float* cs    = ws;
    float* css   = ws + 64;
    int*   Hm    = (int*)(ws + 128);
    int*   Sloc  = Hm + HN;
    int*   bsum  = Sloc + HN;
    int*   bsumx = bsum + 1024;
    int*   S     = bsumx + 1024;
    int*   packed= S + HN;

    hipMemsetAsync(d_ws, 0, 128 * sizeof(float), stream);  // cs/css only

    k_hist_coarse<<<SBLK, 1024, 0, stream>>>(ei, Hm);
    k_scan1<<<HN / 256, 256, 0, stream>>>(Hm, Sloc, bsum);
    k_scan2<<<1, 1024, 0, stream>>>(bsum, bsumx);
    k_scan3<<<HN / 256, 256, 0, stream>>>(Sloc, bsumx, S);
    k_scatter2<<<SBLK, 1024, 0, stream>>>(ei, ea, S, packed);
    k_agg_lds<<<(N_NODESC + 127) / 128, 256, 0, stream>>>(x, emb, S, packed, out);

    const int nblk = (N_NODESC + 63) / 64;
    k_mlp1<<<nblk, 256, 0, stream>>>(x, out, W1, b1, eps, cs, css);
    k_mlp2<<<nblk, 256, 0, stream>>>(out, W2, b2, gamma, beta, cs, css, out);
}

// Round 5
// 275.476 us; speedup vs baseline: 3.3799x; 3.3799x over previous
//
#include <hip/hip_runtime.h>

#define N_NODESC 100000
#define N_EDGESC 1600000
#define BN_EPSC 1e-5f
#define NBUCK 1024              // coarse buckets (dst>>7), 782 used
#define SBLK 256                // scatter/hist blocks
#define EPB (N_EDGESC / SBLK)   // 6250 edges per block
#define HN (NBUCK * SBLK)       // 262144 hist entries

// ---------------------------------------------------------------------------
// K_hist_coarse: per-block histogram over 1024 coarse dst-buckets.
// Hm bucket-major: Hm[b*SBLK + k] = count of block k's edges in bucket b.
// ---------------------------------------------------------------------------
__global__ __launch_bounds__(1024) void k_hist_coarse(
    const int* __restrict__ ei, int* __restrict__ Hm)
{
    __shared__ int h[NBUCK];
    const int t = threadIdx.x;
    const int k = blockIdx.x;
    h[t] = 0;
    __syncthreads();
    const int base = k * EPB;
    #pragma unroll
    for (int i = 0; i < 7; i++) {
        const int e = base + i * 1024 + t;
        if (e < base + EPB) atomicAdd(&h[ei[N_EDGESC + e] >> 7], 1);
    }
    __syncthreads();
    Hm[t * SBLK + k] = h[t];
}

// ---------------------------------------------------------------------------
// K_scan1/2/3: hierarchical exclusive scan of the HN-entry matrix.
// ---------------------------------------------------------------------------
__global__ __launch_bounds__(256) void k_scan1(
    const int* __restrict__ in, int* __restrict__ local, int* __restrict__ bsum)
{
    __shared__ int wsum[4];
    const int t = threadIdx.x;
    const int i = blockIdx.x * 256 + t;
    const int lane = t & 63;
    const int wid = t >> 6;
    const int v = in[i];
    int inc = v;
    #pragma unroll
    for (int d = 1; d < 64; d <<= 1) {
        const int u = __shfl_up(inc, d);
        if (lane >= d) inc += u;
    }
    if (lane == 63) wsum[wid] = inc;
    __syncthreads();
    int add = 0;
    #pragma unroll
    for (int w = 0; w < 3; w++) if (w < wid) add += wsum[w];
    local[i] = inc - v + add;
    if (t == 255) bsum[blockIdx.x] = add + inc;
}

__global__ __launch_bounds__(1024) void k_scan2(
    const int* __restrict__ bsum, int* __restrict__ bsumx)
{
    __shared__ int s[1024];
    const int t = threadIdx.x;
    const int v = bsum[t];
    s[t] = v;
    __syncthreads();
    for (int d = 1; d < 1024; d <<= 1) {
        const int u = (t >= d) ? s[t - d] : 0;
        __syncthreads();
        s[t] += u;
        __syncthreads();
    }
    bsumx[t] = s[t] - v;
}

__global__ __launch_bounds__(256) void k_scan3(
    const int* __restrict__ local, const int* __restrict__ bsumx,
    int* __restrict__ S)
{
    const int i = blockIdx.x * 256 + threadIdx.x;
    S[i] = local[i] + bsumx[blockIdx.x];
}

// ---------------------------------------------------------------------------
// K_scatter2: edges -> coarse buckets (near-contiguous runs per (bucket,blk)).
// tmp = src(17b) | attr<<17(2b) | (dst&127)<<19(7b).
// ---------------------------------------------------------------------------
__global__ __launch_bounds__(1024) void k_scatter2(
    const int* __restrict__ ei, const int* __restrict__ ea,
    const int* __restrict__ S, int* __restrict__ tmp)
{
    __shared__ int lcur[NBUCK];
    const int t = threadIdx.x;
    const int k = blockIdx.x;
    lcur[t] = S[t * SBLK + k];
    __syncthreads();
    const int base = k * EPB;
    #pragma unroll
    for (int i = 0; i < 7; i++) {
        const int e = base + i * 1024 + t;
        if (e < base + EPB) {
            const int src = ei[e];
            const int dst = ei[N_EDGESC + e];
            const int a = ea[e];
            const int pos = atomicAdd(&lcur[dst >> 7], 1);
            tmp[pos] = src | (a << 17) | ((dst & 127) << 19);
        }
    }
}

// ---------------------------------------------------------------------------
// K_bucket_csr: one block per bucket.  Count 128 node degrees in LDS,
// wave-scan, write global CSR off, scatter edges node-sorted into the
// bucket's contiguous final range (all writes in an ~8KB L2-local window).
// packed = src(17b) | attr<<17(2b).
// ---------------------------------------------------------------------------
__global__ __launch_bounds__(256) void k_bucket_csr(
    const int* __restrict__ S, const int* __restrict__ tmp,
    int* __restrict__ off, int* __restrict__ packed)
{
    __shared__ int cnt[128];
    __shared__ int cur[128];
    const int t = threadIdx.x;
    const int b = blockIdx.x;
    if (t < 128) cnt[t] = 0;
    __syncthreads();
    const int start = S[b * SBLK];
    const int end = S[(b + 1) * SBLK];
    for (int e = start + t; e < end; e += 256)
        atomicAdd(&cnt[(tmp[e] >> 19) & 127], 1);
    __syncthreads();
    if (t < 64) {
        const int lane = t;
        const int v0 = cnt[lane];
        const int v1 = cnt[64 + lane];
        int i0 = v0, i1 = v1;
        #pragma unroll
        for (int d = 1; d < 64; d <<= 1) {
            const int u0 = __shfl_up(i0, d);
            const int u1 = __shfl_up(i1, d);
            if (lane >= d) { i0 += u0; i1 += u1; }
        }
        const int tot0 = __shfl(i0, 63);
        const int o0 = start + i0 - v0;
        const int o1 = start + tot0 + i1 - v1;
        cur[lane] = o0;
        cur[64 + lane] = o1;
        const int n0 = b * 128 + lane;
        if (n0 < N_NODESC) off[n0] = o0;
        if (n0 + 64 < N_NODESC) off[n0 + 64] = o1;
    }
    if (b == 0 && t == 64) off[N_NODESC] = N_EDGESC;
    __syncthreads();
    for (int e = start + t; e < end; e += 256) {
        const int p = tmp[e];
        const int pos = atomicAdd(&cur[(p >> 19) & 127], 1);
        packed[pos] = p & 0x7FFFF;
    }
}

// ---------------------------------------------------------------------------
// K_agg: per-node register accumulation.  16 lanes per node (float4 each),
// 4 nodes per wave -> 4 edges in flight per wave; unroll-2 for 2 independent
// x-row loads per iteration.  agg -> d_out (row-aligned overwrite in mlp1).
// ---------------------------------------------------------------------------
__global__ __launch_bounds__(256) void k_agg(
    const float* __restrict__ x, const float* __restrict__ emb,
    const int* __restrict__ off, const int* __restrict__ packed,
    float* __restrict__ agg)
{
    const int t = threadIdx.x;
    const int q = t & 15;
    const int node = blockIdx.x * 16 + (t >> 4);
    const int start = off[node];
    const int end = off[node + 1];
    const float4* x4 = (const float4*)x;
    const float4* e4 = (const float4*)emb;
    float4 acc = make_float4(0.f, 0.f, 0.f, 0.f);
    int e = start;
    for (; e + 2 <= end; e += 2) {
        const int p0 = packed[e];
        const int p1 = packed[e + 1];
        const float4 xv0 = x4[(size_t)(p0 & 0x1FFFF) * 16 + q];
        const float4 xv1 = x4[(size_t)(p1 & 0x1FFFF) * 16 + q];
        const float4 t0 = e4[((p0 >> 17) & 3) * 16 + q];
        const float4 t1 = e4[((p1 >> 17) & 3) * 16 + q];
        acc.x += fmaxf(xv0.x + t0.x, 0.f) + fmaxf(xv1.x + t1.x, 0.f);
        acc.y += fmaxf(xv0.y + t0.y, 0.f) + fmaxf(xv1.y + t1.y, 0.f);
        acc.z += fmaxf(xv0.z + t0.z, 0.f) + fmaxf(xv1.z + t1.z, 0.f);
        acc.w += fmaxf(xv0.w + t0.w, 0.f) + fmaxf(xv1.w + t1.w, 0.f);
    }
    if (e < end) {
        const int p0 = packed[e];
        const float4 xv0 = x4[(size_t)(p0 & 0x1FFFF) * 16 + q];
        const float4 t0 = e4[((p0 >> 17) & 3) * 16 + q];
        acc.x += fmaxf(xv0.x + t0.x, 0.f);
        acc.y += fmaxf(xv0.y + t0.y, 0.f);
        acc.z += fmaxf(xv0.z + t0.z, 0.f);
        acc.w += fmaxf(xv0.w + t0.w, 0.f);
    }
    ((float4*)agg)[(size_t)node * 16 + q] = acc;
}

// ---------------------------------------------------------------------------
// K_mlp1: hbuf := ((1+eps)*x + hbuf) @ W1 + b1 ; accumulate BN column sums.
// ---------------------------------------------------------------------------
__global__ __launch_bounds__(256) void k_mlp1(
    const float* __restrict__ x, float* hbuf,
    const float* __restrict__ W1, const float* __restrict__ b1,
    const float* __restrict__ epsp,
    float* __restrict__ cs, float* __restrict__ css)
{
    __shared__ float lin[64][68];
    __shared__ float lW[4096];
    __shared__ float redS[4][64];
    __shared__ float redQ[4][64];
    const int t = threadIdx.x;
    const int nbase = blockIdx.x * 64;
    const float sc1 = 1.0f + epsp[0];

    {
        const float4* W4 = (const float4*)W1;
        float4* lW4 = (float4*)lW;
        #pragma unroll
        for (int i = 0; i < 4; i++) lW4[i * 256 + t] = W4[i * 256 + t];
    }
    {
        const float4* x4 = (const float4*)x;
        const float4* a4 = (const float4*)hbuf;
        #pragma unroll
        for (int i = 0; i < 4; i++) {
            const int ln = i * 16 + (t >> 4);
            const int q = t & 15;
            const int n = nbase + ln;
            float4 v = make_float4(0.f, 0.f, 0.f, 0.f);
            if (n < N_NODESC) {
                const float4 xv = x4[(size_t)n * 16 + q];
                const float4 av = a4[(size_t)n * 16 + q];
                v.x = fmaf(sc1, xv.x, av.x);
                v.y = fmaf(sc1, xv.y, av.y);
                v.z = fmaf(sc1, xv.z, av.z);
                v.w = fmaf(sc1, xv.w, av.w);
            }
            *(float4*)&lin[ln][q * 4] = v;
        }
    }
    __syncthreads();

    const int r = t >> 2;
    const int g = t & 3;
    const int n = nbase + r;
    const float4* lW4 = (const float4*)lW;
    const float4* b4 = (const float4*)b1;
    float4 acc0 = b4[g * 4 + 0];
    float4 acc1 = b4[g * 4 + 1];
    float4 acc2 = b4[g * 4 + 2];
    float4 acc3 = b4[g * 4 + 3];
    for (int k = 0; k < 64; k++) {
        const float a = lin[r][k];
        const float4 w0 = lW4[k * 16 + g * 4 + 0];
        const float4 w1 = lW4[k * 16 + g * 4 + 1];
        const float4 w2 = lW4[k * 16 + g * 4 + 2];
        const float4 w3 = lW4[k * 16 + g * 4 + 3];
        acc0.x = fmaf(a, w0.x, acc0.x); acc0.y = fmaf(a, w0.y, acc0.y);
        acc0.z = fmaf(a, w0.z, acc0.z); acc0.w = fmaf(a, w0.w, acc0.w);
        acc1.x = fmaf(a, w1.x, acc1.x); acc1.y = fmaf(a, w1.y, acc1.y);
        acc1.z = fmaf(a, w1.z, acc1.z); acc1.w = fmaf(a, w1.w, acc1.w);
        acc2.x = fmaf(a, w2.x, acc2.x); acc2.y = fmaf(a, w2.y, acc2.y);
        acc2.z = fmaf(a, w2.z, acc2.z); acc2.w = fmaf(a, w2.w, acc2.w);
        acc3.x = fmaf(a, w3.x, acc3.x); acc3.y = fmaf(a, w3.y, acc3.y);
        acc3.z = fmaf(a, w3.z, acc3.z); acc3.w = fmaf(a, w3.w, acc3.w);
    }
    if (n < N_NODESC) {
        float4* h4 = (float4*)hbuf;
        h4[(size_t)n * 16 + g * 4 + 0] = acc0;
        h4[(size_t)n * 16 + g * 4 + 1] = acc1;
        h4[(size_t)n * 16 + g * 4 + 2] = acc2;
        h4[(size_t)n * 16 + g * 4 + 3] = acc3;
    }

    float vs[16], vq[16];
    const float msk = (n < N_NODESC) ? 1.0f : 0.0f;
    {
        const float a0[16] = {acc0.x, acc0.y, acc0.z, acc0.w,
                              acc1.x, acc1.y, acc1.z, acc1.w,
                              acc2.x, acc2.y, acc2.z, acc2.w,
                              acc3.x, acc3.y, acc3.z, acc3.w};
        #pragma unroll
        for (int i = 0; i < 16; i++) {
            const float v = a0[i] * msk;
            vs[i] = v;
            vq[i] = v * a0[i];
        }
    }
    #pragma unroll
    for (int off2 = 4; off2 < 64; off2 <<= 1) {
        #pragma unroll
        for (int i = 0; i < 16; i++) {
            vs[i] += __shfl_xor(vs[i], off2);
            vq[i] += __shfl_xor(vq[i], off2);
        }
    }
    const int lane = t & 63;
    const int w = t >> 6;
    if (lane < 4) {
        #pragma unroll
        for (int i = 0; i < 16; i++) {
            redS[w][lane * 16 + i] = vs[i];
            redQ[w][lane * 16 + i] = vq[i];
        }
    }
    __syncthreads();
    if (t < 64) {
        const float s = redS[0][t] + redS[1][t] + redS[2][t] + redS[3][t];
        const float qq = redQ[0][t] + redQ[1][t] + redQ[2][t] + redQ[3][t];
        unsafeAtomicAdd(&cs[t], s);
        unsafeAtomicAdd(&css[t], qq);
    }
}

// ---------------------------------------------------------------------------
// K_mlp2: out = relu(BN(h1)) @ W2 + b2.  h1 aliases out; rows staged to LDS.
// ---------------------------------------------------------------------------
__global__ __launch_bounds__(256) void k_mlp2(
    const float* h1, const float* __restrict__ W2, const float* __restrict__ b2,
    const float* __restrict__ gamma, const float* __restrict__ beta,
    const float* __restrict__ cs, const float* __restrict__ css,
    float* out)
{
    __shared__ float lin[64][68];
    __shared__ float lW[4096];
    __shared__ float scl[64];
    __shared__ float sft[64];
    const int t = threadIdx.x;
    const int nbase = blockIdx.x * 64;

    if (t < 64) {
        const float inv = 1.0f / (float)N_NODESC;
        const float mu = cs[t] * inv;
        const float var = css[t] * inv - mu * mu;
        const float rs = rsqrtf(var + BN_EPSC);
        const float s = rs * gamma[t];
        scl[t] = s;
        sft[t] = fmaf(-mu, s, beta[t]);
    }
    {
        const float4* W4 = (const float4*)W2;
        float4* lW4 = (float4*)lW;
        #pragma unroll
        for (int i = 0; i < 4; i++) lW4[i * 256 + t] = W4[i * 256 + t];
    }
    __syncthreads();
    {
        const float4* h4 = (const float4*)h1;
        #pragma unroll
        for (int i = 0; i < 4; i++) {
            const int ln = i * 16 + (t >> 4);
            const int q = t & 15;
            const int n = nbase + ln;
            float4 v = make_float4(0.f, 0.f, 0.f, 0.f);
            if (n < N_NODESC) {
                const float4 h = h4[(size_t)n * 16 + q];
                const int c = q * 4;
                v.x = fmaxf(fmaf(h.x, scl[c + 0], sft[c + 0]), 0.f);
                v.y = fmaxf(fmaf(h.y, scl[c + 1], sft[c + 1]), 0.f);
                v.z = fmaxf(fmaf(h.z, scl[c + 2], sft[c + 2]), 0.f);
                v.w = fmaxf(fmaf(h.w, scl[c + 3], sft[c + 3]), 0.f);
            }
            *(float4*)&lin[ln][q * 4] = v;
        }
    }
    __syncthreads();

    const int r = t >> 2;
    const int g = t & 3;
    const int n = nbase + r;
    const float4* lW4 = (const float4*)lW;
    const float4* b4 = (const float4*)b2;
    float4 acc0 = b4[g * 4 + 0];
    float4 acc1 = b4[g * 4 + 1];
    float4 acc2 = b4[g * 4 + 2];
    float4 acc3 = b4[g * 4 + 3];
    for (int k = 0; k < 64; k++) {
        const float a = lin[r][k];
        const float4 w0 = lW4[k * 16 + g * 4 + 0];
        const float4 w1 = lW4[k * 16 + g * 4 + 1];
        const float4 w2 = lW4[k * 16 + g * 4 + 2];
        const float4 w3 = lW4[k * 16 + g * 4 + 3];
        acc0.x = fmaf(a, w0.x, acc0.x); acc0.y = fmaf(a, w0.y, acc0.y);
        acc0.z = fmaf(a, w0.z, acc0.z); acc0.w = fmaf(a, w0.w, acc0.w);
        acc1.x = fmaf(a, w1.x, acc1.x); acc1.y = fmaf(a, w1.y, acc1.y);
        acc1.z = fmaf(a, w1.z, acc1.z); acc1.w = fmaf(a, w1.w, acc1.w);
        acc2.x = fmaf(a, w2.x, acc2.x); acc2.y = fmaf(a, w2.y, acc2.y);
        acc2.z = fmaf(a, w2.z, acc2.z); acc2.w = fmaf(a, w2.w, acc2.w);
        acc3.x = fmaf(a, w3.x, acc3.x); acc3.y = fmaf(a, w3.y, acc3.y);
        acc3.z = fmaf(a, w3.z, acc3.z); acc3.w = fmaf(a, w3.w, acc3.w);
    }
    if (n < N_NODESC) {
        float4* o4 = (float4*)out;
        o4[(size_t)n * 16 + g * 4 + 0] = acc0;
        o4[(size_t)n * 16 + g * 4 + 1] = acc1;
        o4[(size_t)n * 16 + g * 4 + 2] = acc2;
        o4[(size_t)n * 16 + g * 4 + 3] = acc3;
    }
}

// ---------------------------------------------------------------------------
extern "C" void kernel_launch(void* const* d_in, const int* in_sizes, int n_in,
                              void* d_out, int out_size, void* d_ws, size_t ws_size,
                              hipStream_t stream) {
    const float* x     = (const float*)d_in[0];
    const float* emb   = (const float*)d_in[1];
    const float* eps   = (const float*)d_in[2];
    const float* W1    = (const float*)d_in[3];
    const float* b1    = (const float*)d_in[4];
    const float* gamma = (const float*)d_in[5];
    const float* beta  = (const float*)d_in[6];
    const float* W2    = (const float*)d_in[7];
    const float* b2    = (const float*)d_in[8];
    const int*   ei    = (const int*)d_in[9];
    const int*   ea    = (const int*)d_in[10];
    float* out = (float*)d_out;

    // ws: [cs 64][css 64][Hm HN][Sloc HN][bsum 1024][bsumx 1024][S HN]
    //     [off N+1][tmp E][packed E]  (~16.4 MB)
    float* ws    = (float*)d_ws;
    float* cs    = ws;
    float* css   = ws + 64;
    int*   Hm    = (int*)(ws + 128);
    int*   Sloc  = Hm + HN;
    int*   bsum  = Sloc + HN;
    int*   bsumx = bsum + 1024;
    int*   S     = bsumx + 1024;
    int*   off   = S + HN;
    int*   tmp   = off + N_NODESC + 1;
    int*   packed= tmp + N_EDGESC;

    hipMemsetAsync(d_ws, 0, 128 * sizeof(float), stream);  // cs/css only

    k_hist_coarse<<<SBLK, 1024, 0, stream>>>(ei, Hm);
    k_scan1<<<HN / 256, 256, 0, stream>>>(Hm, Sloc, bsum);
    k_scan2<<<1, 1024, 0, stream>>>(bsum, bsumx);
    k_scan3<<<HN / 256, 256, 0, stream>>>(Sloc, bsumx, S);
    k_scatter2<<<SBLK, 1024, 0, stream>>>(ei, ea, S, tmp);
    k_bucket_csr<<<782, 256, 0, stream>>>(S, tmp, off, packed);
    k_agg<<<N_NODESC / 16, 256, 0, stream>>>(x, emb, off, packed, out);

    const int nblk = (N_NODESC + 63) / 64;
    k_mlp1<<<nblk, 256, 0, stream>>>(x, out, W1, b1, eps, cs, css);
    k_mlp2<<<nblk, 256, 0, stream>>>(out, W2, b2, gamma, beta, cs, css, out);
}

// Round 6
// 254.528 us; speedup vs baseline: 3.6581x; 1.0823x over previous
//
#include <hip/hip_runtime.h>

#define N_NODESC 100000
#define N_EDGESC 1600000
#define BN_EPSC 1e-5f
#define NBUCK 1024              // coarse buckets (dst>>7), 782 used
#define SBLK 256                // scatter/hist blocks
#define EPB (N_EDGESC / SBLK)   // 6250 edges per block
#define HN (NBUCK * SBLK)       // 262144 hist entries
#define MT 128                  // nodes per MLP block

// ---------------------------------------------------------------------------
// K_hist_coarse: per-block histogram over 1024 coarse dst-buckets.
// Hm bucket-major: Hm[b*SBLK + k] = count of block k's edges in bucket b.
// ---------------------------------------------------------------------------
__global__ __launch_bounds__(1024) void k_hist_coarse(
    const int* __restrict__ ei, int* __restrict__ Hm)
{
    __shared__ int h[NBUCK];
    const int t = threadIdx.x;
    const int k = blockIdx.x;
    h[t] = 0;
    __syncthreads();
    const int base = k * EPB;
    #pragma unroll
    for (int i = 0; i < 7; i++) {
        const int e = base + i * 1024 + t;
        if (e < base + EPB) atomicAdd(&h[ei[N_EDGESC + e] >> 7], 1);
    }
    __syncthreads();
    Hm[t * SBLK + k] = h[t];
}

// ---------------------------------------------------------------------------
// K_scan1: per-256-chunk exclusive scan + chunk totals.  Chunk c of the
// bucket-major matrix is exactly bucket c (SBLK==256), so bsum[c] = bucket
// c's edge count and Sloc[i]+bsumx[i>>8] is the global exclusive scan.
// ---------------------------------------------------------------------------
__global__ __launch_bounds__(256) void k_scan1(
    const int* __restrict__ in, int* __restrict__ local, int* __restrict__ bsum)
{
    __shared__ int wsum[4];
    const int t = threadIdx.x;
    const int i = blockIdx.x * 256 + t;
    const int lane = t & 63;
    const int wid = t >> 6;
    const int v = in[i];
    int inc = v;
    #pragma unroll
    for (int d = 1; d < 64; d <<= 1) {
        const int u = __shfl_up(inc, d);
        if (lane >= d) inc += u;
    }
    if (lane == 63) wsum[wid] = inc;
    __syncthreads();
    int add = 0;
    #pragma unroll
    for (int w = 0; w < 3; w++) if (w < wid) add += wsum[w];
    local[i] = inc - v + add;
    if (t == 255) bsum[blockIdx.x] = add + inc;
}

__global__ __launch_bounds__(1024) void k_scan2(
    const int* __restrict__ bsum, int* __restrict__ bsumx)
{
    __shared__ int s[1024];
    const int t = threadIdx.x;
    const int v = bsum[t];
    s[t] = v;
    __syncthreads();
    for (int d = 1; d < 1024; d <<= 1) {
        const int u = (t >= d) ? s[t - d] : 0;
        __syncthreads();
        s[t] += u;
        __syncthreads();
    }
    bsumx[t] = s[t] - v;
}

// ---------------------------------------------------------------------------
// K_scatter2: edges -> coarse buckets.  S[i] = Sloc[i] + bsumx[i>>8] inline.
// tmp = src(17b) | attr<<17(2b) | (dst&127)<<19(7b).
// ---------------------------------------------------------------------------
__global__ __launch_bounds__(1024) void k_scatter2(
    const int* __restrict__ ei, const int* __restrict__ ea,
    const int* __restrict__ Sloc, const int* __restrict__ bsumx,
    int* __restrict__ tmp)
{
    __shared__ int lcur[NBUCK];
    const int t = threadIdx.x;
    const int k = blockIdx.x;
    lcur[t] = Sloc[t * SBLK + k] + bsumx[t];
    __syncthreads();
    const int base = k * EPB;
    #pragma unroll
    for (int i = 0; i < 7; i++) {
        const int e = base + i * 1024 + t;
        if (e < base + EPB) {
            const int src = ei[e];
            const int dst = ei[N_EDGESC + e];
            const int a = ea[e];
            const int pos = atomicAdd(&lcur[dst >> 7], 1);
            tmp[pos] = src | (a << 17) | ((dst & 127) << 19);
        }
    }
}

// ---------------------------------------------------------------------------
// K_bucket_csr: one block per bucket.  Count 128 node degrees, wave-scan,
// write global CSR off, scatter edges node-sorted into the bucket's
// contiguous final range.  packed = src(17b) | attr<<17(2b).
// ---------------------------------------------------------------------------
__global__ __launch_bounds__(256) void k_bucket_csr(
    const int* __restrict__ Sloc, const int* __restrict__ bsumx,
    const int* __restrict__ tmp,
    int* __restrict__ off, int* __restrict__ packed)
{
    __shared__ int cnt[128];
    __shared__ int cur[128];
    const int t = threadIdx.x;
    const int b = blockIdx.x;
    if (t < 128) cnt[t] = 0;
    __syncthreads();
    const int start = Sloc[b * 256] + bsumx[b];
    const int end = (b == NBUCK - 1) ? N_EDGESC
                                     : (Sloc[(b + 1) * 256] + bsumx[b + 1]);
    for (int e = start + t; e < end; e += 256)
        atomicAdd(&cnt[(tmp[e] >> 19) & 127], 1);
    __syncthreads();
    if (t < 64) {
        const int lane = t;
        const int v0 = cnt[lane];
        const int v1 = cnt[64 + lane];
        int i0 = v0, i1 = v1;
        #pragma unroll
        for (int d = 1; d < 64; d <<= 1) {
            const int u0 = __shfl_up(i0, d);
            const int u1 = __shfl_up(i1, d);
            if (lane >= d) { i0 += u0; i1 += u1; }
        }
        const int tot0 = __shfl(i0, 63);
        const int o0 = start + i0 - v0;
        const int o1 = start + tot0 + i1 - v1;
        cur[lane] = o0;
        cur[64 + lane] = o1;
        const int n0 = b * 128 + lane;
        if (n0 < N_NODESC) off[n0] = o0;
        if (n0 + 64 < N_NODESC) off[n0 + 64] = o1;
    }
    if (b == 0 && t == 64) off[N_NODESC] = N_EDGESC;
    __syncthreads();
    for (int e = start + t; e < end; e += 256) {
        const int p = tmp[e];
        const int pos = atomicAdd(&cur[(p >> 19) & 127], 1);
        packed[pos] = p & 0x7FFFF;
    }
}

// ---------------------------------------------------------------------------
// K_agg: per-node register accumulation (16 lanes/node, unroll-2).
// ---------------------------------------------------------------------------
__global__ __launch_bounds__(256) void k_agg(
    const float* __restrict__ x, const float* __restrict__ emb,
    const int* __restrict__ off, const int* __restrict__ packed,
    float* __restrict__ agg)
{
    const int t = threadIdx.x;
    const int q = t & 15;
    const int node = blockIdx.x * 16 + (t >> 4);
    const int start = off[node];
    const int end = off[node + 1];
    const float4* x4 = (const float4*)x;
    const float4* e4 = (const float4*)emb;
    float4 acc = make_float4(0.f, 0.f, 0.f, 0.f);
    int e = start;
    for (; e + 2 <= end; e += 2) {
        const int p0 = packed[e];
        const int p1 = packed[e + 1];
        const float4 xv0 = x4[(size_t)(p0 & 0x1FFFF) * 16 + q];
        const float4 xv1 = x4[(size_t)(p1 & 0x1FFFF) * 16 + q];
        const float4 t0 = e4[((p0 >> 17) & 3) * 16 + q];
        const float4 t1 = e4[((p1 >> 17) & 3) * 16 + q];
        acc.x += fmaxf(xv0.x + t0.x, 0.f) + fmaxf(xv1.x + t1.x, 0.f);
        acc.y += fmaxf(xv0.y + t0.y, 0.f) + fmaxf(xv1.y + t1.y, 0.f);
        acc.z += fmaxf(xv0.z + t0.z, 0.f) + fmaxf(xv1.z + t1.z, 0.f);
        acc.w += fmaxf(xv0.w + t0.w, 0.f) + fmaxf(xv1.w + t1.w, 0.f);
    }
    if (e < end) {
        const int p0 = packed[e];
        const float4 xv0 = x4[(size_t)(p0 & 0x1FFFF) * 16 + q];
        const float4 t0 = e4[((p0 >> 17) & 3) * 16 + q];
        acc.x += fmaxf(xv0.x + t0.x, 0.f);
        acc.y += fmaxf(xv0.y + t0.y, 0.f);
        acc.z += fmaxf(xv0.z + t0.z, 0.f);
        acc.w += fmaxf(xv0.w + t0.w, 0.f);
    }
    ((float4*)agg)[(size_t)node * 16 + q] = acc;
}

// ---------------------------------------------------------------------------
// K_mlp1: hbuf := ((1+eps)*x + hbuf) @ W1 + b1 ; BN column sums.
// 128 nodes/block; thread = (colgroup g = t&7 -> 8 cols, rowgroup r0 = t>>3
// -> nodes r0+32j).  Per k: 4 ds_read_b32 (8-lane bcast, 8 distinct banks) +
// 2 ds_read_b128 per 32 v_fma_f32x4 -> VALU-bound.
// ---------------------------------------------------------------------------
__global__ __launch_bounds__(256) void k_mlp1(
    const float* __restrict__ x, float* hbuf,
    const float* __restrict__ W1, const float* __restrict__ b1,
    const float* __restrict__ epsp,
    float* __restrict__ cs, float* __restrict__ css)
{
    __shared__ float lin[MT][68];     // stride 68: rows 16B-aligned
    __shared__ float lW[4096];
    __shared__ float redS[4][64];
    __shared__ float redQ[4][64];
    const int t = threadIdx.x;
    const int nbase = blockIdx.x * MT;
    const float sc1 = 1.0f + epsp[0];

    {   // stage W1 (64x64) -> LDS
        const float4* W4 = (const float4*)W1;
        float4* lW4 = (float4*)lW;
        #pragma unroll
        for (int i = 0; i < 4; i++) lW4[i * 256 + t] = W4[i * 256 + t];
    }
    {   // stage 128 rows: (1+eps)*x + agg
        const float4* x4 = (const float4*)x;
        const float4* a4 = (const float4*)hbuf;
        #pragma unroll
        for (int i = 0; i < 8; i++) {
            const int fidx = i * 256 + t;
            const int row = fidx >> 4;
            const int q = fidx & 15;
            const int n = nbase + row;
            float4 v = make_float4(0.f, 0.f, 0.f, 0.f);
            if (n < N_NODESC) {
                const float4 xv = x4[(size_t)n * 16 + q];
                const float4 av = a4[(size_t)n * 16 + q];
                v.x = fmaf(sc1, xv.x, av.x);
                v.y = fmaf(sc1, xv.y, av.y);
                v.z = fmaf(sc1, xv.z, av.z);
                v.w = fmaf(sc1, xv.w, av.w);
            }
            *(float4*)&lin[row][q * 4] = v;
        }
    }
    __syncthreads();   // also orders agg reads before hbuf overwrite

    const int g = t & 7;     // cols g*8..g*8+7  (float4 slots g*2, g*2+1)
    const int r0 = t >> 3;   // nodes r0 + 32j
    const float4* lW4 = (const float4*)lW;
    const float4* b4 = (const float4*)b1;
    const float4 bb0 = b4[g * 2 + 0];
    const float4 bb1 = b4[g * 2 + 1];
    float4 a00 = bb0, a01 = bb1, a10 = bb0, a11 = bb1;
    float4 a20 = bb0, a21 = bb1, a30 = bb0, a31 = bb1;
    for (int k = 0; k < 64; k++) {
        const float v0 = lin[r0][k];
        const float v1 = lin[r0 + 32][k];
        const float v2 = lin[r0 + 64][k];
        const float v3 = lin[r0 + 96][k];
        const float4 w0 = lW4[k * 16 + g * 2 + 0];
        const float4 w1 = lW4[k * 16 + g * 2 + 1];
        a00.x = fmaf(v0, w0.x, a00.x); a00.y = fmaf(v0, w0.y, a00.y);
        a00.z = fmaf(v0, w0.z, a00.z); a00.w = fmaf(v0, w0.w, a00.w);
        a01.x = fmaf(v0, w1.x, a01.x); a01.y = fmaf(v0, w1.y, a01.y);
        a01.z = fmaf(v0, w1.z, a01.z); a01.w = fmaf(v0, w1.w, a01.w);
        a10.x = fmaf(v1, w0.x, a10.x); a10.y = fmaf(v1, w0.y, a10.y);
        a10.z = fmaf(v1, w0.z, a10.z); a10.w = fmaf(v1, w0.w, a10.w);
        a11.x = fmaf(v1, w1.x, a11.x); a11.y = fmaf(v1, w1.y, a11.y);
        a11.z = fmaf(v1, w1.z, a11.z); a11.w = fmaf(v1, w1.w, a11.w);
        a20.x = fmaf(v2, w0.x, a20.x); a20.y = fmaf(v2, w0.y, a20.y);
        a20.z = fmaf(v2, w0.z, a20.z); a20.w = fmaf(v2, w0.w, a20.w);
        a21.x = fmaf(v2, w1.x, a21.x); a21.y = fmaf(v2, w1.y, a21.y);
        a21.z = fmaf(v2, w1.z, a21.z); a21.w = fmaf(v2, w1.w, a21.w);
        a30.x = fmaf(v3, w0.x, a30.x); a30.y = fmaf(v3, w0.y, a30.y);
        a30.z = fmaf(v3, w0.z, a30.z); a30.w = fmaf(v3, w0.w, a30.w);
        a31.x = fmaf(v3, w1.x, a31.x); a31.y = fmaf(v3, w1.y, a31.y);
        a31.z = fmaf(v3, w1.z, a31.z); a31.w = fmaf(v3, w1.w, a31.w);
    }

    float4 A0[4] = {a00, a10, a20, a30};
    float4 A1[4] = {a01, a11, a21, a31};
    float4* h4 = (float4*)hbuf;
    float msk[4];
    #pragma unroll
    for (int j = 0; j < 4; j++) {
        const int n = nbase + r0 + 32 * j;
        msk[j] = (n < N_NODESC) ? 1.0f : 0.0f;
        if (n < N_NODESC) {
            h4[(size_t)n * 16 + g * 2 + 0] = A0[j];
            h4[(size_t)n * 16 + g * 2 + 1] = A1[j];
        }
    }

    // BN partial stats for this thread's 8 cols over its 4 nodes
    float vs[8], vq[8];
    #pragma unroll
    for (int c = 0; c < 8; c++) { vs[c] = 0.f; vq[c] = 0.f; }
    #pragma unroll
    for (int j = 0; j < 4; j++) {
        const float e0[8] = {A0[j].x, A0[j].y, A0[j].z, A0[j].w,
                             A1[j].x, A1[j].y, A1[j].z, A1[j].w};
        #pragma unroll
        for (int c = 0; c < 8; c++) {
            const float v = e0[c] * msk[j];
            vs[c] += v;
            vq[c] += v * e0[c];
        }
    }
    // reduce across the 8 r0-values within the wave (lane bits 3..5)
    #pragma unroll
    for (int o = 8; o < 64; o <<= 1) {
        #pragma unroll
        for (int c = 0; c < 8; c++) {
            vs[c] += __shfl_xor(vs[c], o);
            vq[c] += __shfl_xor(vq[c], o);
        }
    }
    const int lane = t & 63;
    const int w = t >> 6;
    if (lane < 8) {
        #pragma unroll
        for (int c = 0; c < 8; c++) {
            redS[w][lane * 8 + c] = vs[c];
            redQ[w][lane * 8 + c] = vq[c];
        }
    }
    __syncthreads();
    if (t < 64) {
        const float s = redS[0][t] + redS[1][t] + redS[2][t] + redS[3][t];
        const float qq = redQ[0][t] + redQ[1][t] + redQ[2][t] + redQ[3][t];
        unsafeAtomicAdd(&cs[t], s);
        unsafeAtomicAdd(&css[t], qq);
    }
}

// ---------------------------------------------------------------------------
// K_mlp2: out = relu(BN(h1)) @ W2 + b2.  Same register tiling; h1 aliases
// out, rows staged to LDS before overwrite.
// ---------------------------------------------------------------------------
__global__ __launch_bounds__(256) void k_mlp2(
    const float* h1, const float* __restrict__ W2, const float* __restrict__ b2,
    const float* __restrict__ gamma, const float* __restrict__ beta,
    const float* __restrict__ cs, const float* __restrict__ css,
    float* out)
{
    __shared__ float lin[MT][68];
    __shared__ float lW[4096];
    __shared__ float scl[64];
    __shared__ float sft[64];
    const int t = threadIdx.x;
    const int nbase = blockIdx.x * MT;

    if (t < 64) {
        const float inv = 1.0f / (float)N_NODESC;
        const float mu = cs[t] * inv;
        const float var = css[t] * inv - mu * mu;
        const float rs = rsqrtf(var + BN_EPSC);
        const float s = rs * gamma[t];
        scl[t] = s;
        sft[t] = fmaf(-mu, s, beta[t]);
    }
    {
        const float4* W4 = (const float4*)W2;
        float4* lW4 = (float4*)lW;
        #pragma unroll
        for (int i = 0; i < 4; i++) lW4[i * 256 + t] = W4[i * 256 + t];
    }
    __syncthreads();   // scl/sft ready
    {
        const float4* h4 = (const float4*)h1;
        #pragma unroll
        for (int i = 0; i < 8; i++) {
            const int fidx = i * 256 + t;
            const int row = fidx >> 4;
            const int q = fidx & 15;
            const int n = nbase + row;
            float4 v = make_float4(0.f, 0.f, 0.f, 0.f);
            if (n < N_NODESC) {
                const float4 h = h4[(size_t)n * 16 + q];
                const int c = q * 4;
                v.x = fmaxf(fmaf(h.x, scl[c + 0], sft[c + 0]), 0.f);
                v.y = fmaxf(fmaf(h.y, scl[c + 1], sft[c + 1]), 0.f);
                v.z = fmaxf(fmaf(h.z, scl[c + 2], sft[c + 2]), 0.f);
                v.w = fmaxf(fmaf(h.w, scl[c + 3], sft[c + 3]), 0.f);
            }
            *(float4*)&lin[row][q * 4] = v;
        }
    }
    __syncthreads();   // all h1 reads done before overwrite

    const int g = t & 7;
    const int r0 = t >> 3;
    const float4* lW4 = (const float4*)lW;
    const float4* b4 = (const float4*)b2;
    const float4 bb0 = b4[g * 2 + 0];
    const float4 bb1 = b4[g * 2 + 1];
    float4 a00 = bb0, a01 = bb1, a10 = bb0, a11 = bb1;
    float4 a20 = bb0, a21 = bb1, a30 = bb0, a31 = bb1;
    for (int k = 0; k < 64; k++) {
        const float v0 = lin[r0][k];
        const float v1 = lin[r0 + 32][k];
        const float v2 = lin[r0 + 64][k];
        const float v3 = lin[r0 + 96][k];
        const float4 w0 = lW4[k * 16 + g * 2 + 0];
        const float4 w1 = lW4[k * 16 + g * 2 + 1];
        a00.x = fmaf(v0, w0.x, a00.x); a00.y = fmaf(v0, w0.y, a00.y);
        a00.z = fmaf(v0, w0.z, a00.z); a00.w = fmaf(v0, w0.w, a00.w);
        a01.x = fmaf(v0, w1.x, a01.x); a01.y = fmaf(v0, w1.y, a01.y);
        a01.z = fmaf(v0, w1.z, a01.z); a01.w = fmaf(v0, w1.w, a01.w);
        a10.x = fmaf(v1, w0.x, a10.x); a10.y = fmaf(v1, w0.y, a10.y);
        a10.z = fmaf(v1, w0.z, a10.z); a10.w = fmaf(v1, w0.w, a10.w);
        a11.x = fmaf(v1, w1.x, a11.x); a11.y = fmaf(v1, w1.y, a11.y);
        a11.z = fmaf(v1, w1.z, a11.z); a11.w = fmaf(v1, w1.w, a11.w);
        a20.x = fmaf(v2, w0.x, a20.x); a20.y = fmaf(v2, w0.y, a20.y);
        a20.z = fmaf(v2, w0.z, a20.z); a20.w = fmaf(v2, w0.w, a20.w);
        a21.x = fmaf(v2, w1.x, a21.x); a21.y = fmaf(v2, w1.y, a21.y);
        a21.z = fmaf(v2, w1.z, a21.z); a21.w = fmaf(v2, w1.w, a21.w);
        a30.x = fmaf(v3, w0.x, a30.x); a30.y = fmaf(v3, w0.y, a30.y);
        a30.z = fmaf(v3, w0.z, a30.z); a30.w = fmaf(v3, w0.w, a30.w);
        a31.x = fmaf(v3, w1.x, a31.x); a31.y = fmaf(v3, w1.y, a31.y);
        a31.z = fmaf(v3, w1.z, a31.z); a31.w = fmaf(v3, w1.w, a31.w);
    }
    const float4 A0[4] = {a00, a10, a20, a30};
    const float4 A1[4] = {a01, a11, a21, a31};
    float4* o4 = (float4*)out;
    #pragma unroll
    for (int j = 0; j < 4; j++) {
        const int n = nbase + r0 + 32 * j;
        if (n < N_NODESC) {
            o4[(size_t)n * 16 + g * 2 + 0] = A0[j];
            o4[(size_t)n * 16 + g * 2 + 1] = A1[j];
        }
    }
}

// ---------------------------------------------------------------------------
extern "C" void kernel_launch(void* const* d_in, const int* in_sizes, int n_in,
                              void* d_out, int out_size, void* d_ws, size_t ws_size,
                              hipStream_t stream) {
    const float* x     = (const float*)d_in[0];
    const float* emb   = (const float*)d_in[1];
    const float* eps   = (const float*)d_in[2];
    const float* W1    = (const float*)d_in[3];
    const float* b1    = (const float*)d_in[4];
    const float* gamma = (const float*)d_in[5];
    const float* beta  = (const float*)d_in[6];
    const float* W2    = (const float*)d_in[7];
    const float* b2    = (const float*)d_in[8];
    const int*   ei    = (const int*)d_in[9];
    const int*   ea    = (const int*)d_in[10];
    float* out = (float*)d_out;

    // ws: [cs 64][css 64][Hm HN][Sloc HN][bsum 1024][bsumx 1024]
    //     [off N+1][tmp E][packed E]
    float* ws    = (float*)d_ws;
    float* cs    = ws;
    float* css   = ws + 64;
    int*   Hm    = (int*)(ws + 128);
    int*   Sloc  = Hm + HN;
    int*   bsum  = Sloc + HN;
    int*   bsumx = bsum + 1024;
    int*   off   = bsumx + 1024;
    int*   tmp   = off + N_NODESC + 1;
    int*   packed= tmp + N_EDGESC;

    hipMemsetAsync(d_ws, 0, 128 * sizeof(float), stream);  // cs/css only

    k_hist_coarse<<<SBLK, 1024, 0, stream>>>(ei, Hm);
    k_scan1<<<HN / 256, 256, 0, stream>>>(Hm, Sloc, bsum);
    k_scan2<<<1, 1024, 0, stream>>>(bsum, bsumx);
    k_scatter2<<<SBLK, 1024, 0, stream>>>(ei, ea, Sloc, bsumx, tmp);
    k_bucket_csr<<<782, 256, 0, stream>>>(Sloc, bsumx, tmp, off, packed);
    k_agg<<<N_NODESC / 16, 256, 0, stream>>>(x, emb, off, packed, out);

    const int nblk = (N_NODESC + MT - 1) / MT;   // 782
    k_mlp1<<<nblk, 256, 0, stream>>>(x, out, W1, b1, eps, cs, css);
    k_mlp2<<<nblk, 256, 0, stream>>>(out, W2, b2, gamma, beta, cs, css, out);
}